// Round 9
// baseline (349.088 us; speedup 1.0000x reference)
//
#include <hip/hip_runtime.h>
#include <stdint.h>

// B=8, S=1024, D_MODEL=256, dk=dv=16, 128 pseudo-heads of 1024x16.
// ws layout (floats): Q[2M] | K[2M] | V[2M] | AO[2M] -> 32 MB.

typedef _Float16 f16x8 __attribute__((ext_vector_type(8)));
typedef _Float16 f16x4 __attribute__((ext_vector_type(4)));
typedef _Float16 f16x2 __attribute__((ext_vector_type(2)));
typedef float    f32x4 __attribute__((ext_vector_type(4)));

// ---------------------------------------------------------------------------
// Split-f16 MFMA GEMM (unchanged from R8): C[8192x256] = A @ W + bias.
// ---------------------------------------------------------------------------
__device__ __forceinline__ void gemm_mfma(const float* __restrict__ A,
                                          const float* __restrict__ W,
                                          const float* __restrict__ bias,
                                          float* __restrict__ C)
{
    __shared__ _Float16 Bhi[64][264];
    __shared__ _Float16 Blo[64][264];
    const int tid = threadIdx.x;
    const int m0 = blockIdx.x << 6, n0 = blockIdx.y << 6;

    {
        const int kk = (tid & 127) << 1;
        const int nh = (tid >> 7) << 5;
        const float* w0 = W + (size_t)kk * 256 + n0 + nh;
        const float* w1 = w0 + 256;
        #pragma unroll
        for (int c4 = 0; c4 < 8; ++c4) {
            float4 v0 = *(const float4*)(w0 + (c4 << 2));
            float4 v1 = *(const float4*)(w1 + (c4 << 2));
            const float e0[4] = {v0.x, v0.y, v0.z, v0.w};
            const float e1[4] = {v1.x, v1.y, v1.z, v1.w};
            #pragma unroll
            for (int jj = 0; jj < 4; ++jj) {
                const int n = nh + (c4 << 2) + jj;
                _Float16 h0 = (_Float16)e0[jj];
                _Float16 h1 = (_Float16)e1[jj];
                f16x2 hp; hp[0] = h0; hp[1] = h1;
                f16x2 lp; lp[0] = (_Float16)(e0[jj] - (float)h0);
                          lp[1] = (_Float16)(e1[jj] - (float)h1);
                *(f16x2*)&Bhi[n][kk] = hp;
                *(f16x2*)&Blo[n][kk] = lp;
            }
        }
    }
    __syncthreads();

    const int wv = tid >> 6, lane = tid & 63;
    const int fm = lane & 15, fq = lane >> 4;
    const int arow = m0 + (wv << 4) + fm;

    f32x4 acc[4];
    #pragma unroll
    for (int cb = 0; cb < 4; ++cb) { acc[cb][0]=0.f; acc[cb][1]=0.f; acc[cb][2]=0.f; acc[cb][3]=0.f; }

    #pragma unroll
    for (int kb = 0; kb < 8; ++kb) {
        const float* ap = A + (size_t)arow * 256 + (kb << 5) + (fq << 3);
        float4 a0 = *(const float4*)ap;
        float4 a1 = *(const float4*)(ap + 4);
        const float ae[8] = {a0.x, a0.y, a0.z, a0.w, a1.x, a1.y, a1.z, a1.w};
        f16x8 Ah, Al;
        #pragma unroll
        for (int j = 0; j < 8; ++j) {
            _Float16 h = (_Float16)ae[j];
            Ah[j] = h;
            Al[j] = (_Float16)(ae[j] - (float)h);
        }
        #pragma unroll
        for (int cb = 0; cb < 4; ++cb) {
            f16x8 Bh = *(const f16x8*)&Bhi[(cb << 4) + fm][(kb << 5) + (fq << 3)];
            f16x8 Bl = *(const f16x8*)&Blo[(cb << 4) + fm][(kb << 5) + (fq << 3)];
            acc[cb] = __builtin_amdgcn_mfma_f32_16x16x32_f16(Ah, Bh, acc[cb], 0, 0, 0);
            acc[cb] = __builtin_amdgcn_mfma_f32_16x16x32_f16(Al, Bh, acc[cb], 0, 0, 0);
            acc[cb] = __builtin_amdgcn_mfma_f32_16x16x32_f16(Ah, Bl, acc[cb], 0, 0, 0);
        }
    }

    #pragma unroll
    for (int cb = 0; cb < 4; ++cb) {
        const float bb = bias[n0 + (cb << 4) + fm];
        #pragma unroll
        for (int i = 0; i < 4; ++i)
            C[(size_t)(m0 + (wv << 4) + (fq << 2) + i) * 256
              + n0 + (cb << 4) + fm] = acc[cb][i] + bb;
    }
}

__global__ __attribute__((amdgpu_waves_per_eu(2, 2)))
__launch_bounds__(256) void gemmQKV(
    const float* __restrict__ x, const float* __restrict__ y,
    const float* __restrict__ Wq, const float* __restrict__ bq,
    const float* __restrict__ Wk, const float* __restrict__ bk,
    const float* __restrict__ Wv, const float* __restrict__ bv,
    float* __restrict__ Q, float* __restrict__ K, float* __restrict__ V)
{
    const int z = blockIdx.z;
    const float* A = (z == 0) ? x  : y;
    const float* W = (z == 0) ? Wq : (z == 1) ? Wk : Wv;
    const float* b = (z == 0) ? bq : (z == 1) ? bk : bv;
    float*       C = (z == 0) ? Q  : (z == 1) ? K  : V;
    gemm_mfma(A, W, b, C);
}

__global__ __attribute__((amdgpu_waves_per_eu(2, 2)))
__launch_bounds__(256) void gemmOut(
    const float* __restrict__ A, const float* __restrict__ W,
    const float* __restrict__ b, float* __restrict__ C)
{
    gemm_mfma(A, W, b, C);
}

// ---------------------------------------------------------------------------
// Attention
// ---------------------------------------------------------------------------
__device__ __forceinline__ float u2f(unsigned int m) {
    unsigned int x = (m & 0x80000000u) ? (m ^ 0x80000000u) : ~m;
    return __uint_as_float(x);
}
__device__ __forceinline__ unsigned int f2u(float f) {
    unsigned int x = __float_as_uint(f);
    return (x & 0x80000000u) ? ~x : (x | 0x80000000u);
}

// grid (128 heads, 6 groups) = 768 blocks = 3/CU at waves_per_eu(6,6).
// LDS: union{Ssc f32[8][1024]; Vt f16[16][1024]} 32K + P f16[8][1024] 16K
//      + part 4K + sums = 53.3 KB -> 3 blocks = 159.9 KB (just fits).
// P is XOR-octet-swizzled (octet' = octet ^ (row&7)): balanced banks on both
// the phase-2.5 b64 writes and phase-3 b128 A-frag reads. A-frag rows 8-15
// read row fm&7 (duplicates) -> C rows 8-15 garbage, never stored.
// Phase-1 packs the 3 split terms into 2 MFMAs via k-duplication:
//   c = mfma32([Ah|Ah],[Bh|Bl]) + mfma32([Al|0],[Bh|Bl])
//     = AhBh + AhBl + AlBh      (A/B share the (fq,j)->k map; perm cancels)
__global__ __attribute__((amdgpu_waves_per_eu(6, 6)))
__launch_bounds__(512) void attn(
    const float* __restrict__ Qb, const float* __restrict__ Kb,
    const float* __restrict__ Vb, float* __restrict__ Ob)
{
    __shared__ union {
        float    Ssc[8][1024];
        _Float16 Vt[16][1024];
    } U;
    __shared__ _Float16 P[8][1024];   // swizzled probs
    __shared__ float part[1024];      // [8 waves][8 rows][16 d]
    __shared__ float sums[2][8];

    const int tid  = threadIdx.x;
    const int wave = tid >> 6, lane = tid & 63;
    const int head = blockIdx.x, grp = blockIdx.y;
    const float* Qh = Qb + ((size_t)head << 14);
    const float* Kh = Kb + ((size_t)head << 14);
    const float* Vh = Vb + ((size_t)head << 14);
    const int fm = lane & 15, fq = lane >> 4;

    // ---- stage V transposed (f16) into the union, grab register fragments ----
    for (int i = tid; i < 4096; i += 512) {
        float4 v = ((const float4*)Vh)[i];
        const int k = i >> 2, d0 = (i & 3) << 2;
        U.Vt[d0 + 0][k] = (_Float16)v.x;
        U.Vt[d0 + 1][k] = (_Float16)v.y;
        U.Vt[d0 + 2][k] = (_Float16)v.z;
        U.Vt[d0 + 3][k] = (_Float16)v.w;
    }
    __syncthreads();
    f16x8 Vf[4];
    #pragma unroll
    for (int kb = 0; kb < 4; ++kb)
        Vf[kb] = *(const f16x8*)&U.Vt[fm][(((wave << 2) + kb) << 5) + (fq << 3)];

    // ---- K fragments packed [Bh|Bl] f16x8, K pre-scaled by 1/8 ----
    f16x8 Bp[8];
    #pragma unroll
    for (int kb = 0; kb < 8; ++kb) {
        const int krow = (wave << 7) + (kb << 4) + fm;
        float4 kv = *(const float4*)(Kh + ((size_t)krow << 4) + (fq << 2));
        const float ke[4] = {kv.x * 0.125f, kv.y * 0.125f,
                             kv.z * 0.125f, kv.w * 0.125f};
        #pragma unroll
        for (int j = 0; j < 4; ++j) {
            _Float16 h = (_Float16)ke[j];
            Bp[kb][j]     = h;
            Bp[kb][j + 4] = (_Float16)(ke[j] - (float)h);
        }
    }
    __syncthreads();               // Vf reads done before Ssc overwrites Vt

    const int cstart = (grp * 128) / 6;
    const int cend   = ((grp + 1) * 128) / 6;

    for (int chunk = cstart; chunk < cend; ++chunk) {
        const int qbase = chunk << 3;
        const int sb = chunk & 1;

        // ---- phase 1: S = Q K^T/8, 2 packed MFMAs per 16-col tile ----
        f16x8 A1, A2;
        {
            const int arow = qbase + (fm & 7);
            float4 qv = *(const float4*)(Qh + ((size_t)arow << 4) + (fq << 2));
            const float qe[4] = {qv.x, qv.y, qv.z, qv.w};
            #pragma unroll
            for (int j = 0; j < 4; ++j) {
                _Float16 h = (_Float16)qe[j];
                A1[j] = h; A1[j + 4] = h;
                A2[j] = (_Float16)(qe[j] - (float)h);
                A2[j + 4] = (_Float16)0.f;
            }
        }
        #pragma unroll
        for (int kb = 0; kb < 8; ++kb) {
            f32x4 c = {0.f, 0.f, 0.f, 0.f};
            c = __builtin_amdgcn_mfma_f32_16x16x32_f16(A1, Bp[kb], c, 0, 0, 0);
            c = __builtin_amdgcn_mfma_f32_16x16x32_f16(A2, Bp[kb], c, 0, 0, 0);
            if (fq < 2) {
                const int col = (wave << 7) + (kb << 4) + fm;
                #pragma unroll
                for (int i = 0; i < 4; ++i)
                    U.Ssc[(fq << 2) + i][col] = c[i];
            }
        }
        __syncthreads();   // B1: scores visible

        // ---- wave w owns row w; contiguous b128 reads (Ssc stays valid) ----
        float s[16];
        #pragma unroll
        for (int b = 0; b < 4; ++b) {
            f32x4 v = *(const f32x4*)&U.Ssc[wave][(b << 8) + (lane << 2)];
            s[(b << 2) + 0] = v.x; s[(b << 2) + 1] = v.y;
            s[(b << 2) + 2] = v.z; s[(b << 2) + 3] = v.w;
        }
        // (no barrier: P no longer aliases Ssc)

        // ---- phase 2: exact lower median (512th smallest) ----
        float mn = 0.f;
        #pragma unroll
        for (int j = 0; j < 16; ++j) mn += s[j];
        #pragma unroll
        for (int off = 32; off > 0; off >>= 1) mn += __shfl_xor(mn, off);
        mn *= (1.0f / 1024.0f);
        const float step = 0.0012239f;   // sigma~0.5: 0.5*2.5066/1024

        unsigned int lo = 0x00800000u, hi = 0xFF7FFFFFu;
        int cl = 0, ch = 1024;
        float vL = -3.4e38f, vH = 3.4e38f;
        float t = mn, medf = 0.f;
        int found = 0;
        for (int pass = 0; pass < 64 && !found; ++pass) {
            int cnt = 0;
            #pragma unroll
            for (int j = 0; j < 16; ++j)
                cnt += __popcll(__ballot(s[j] <= t));
            const unsigned int tc = f2u(t);
            if (cnt >= 512) { hi = tc; ch = cnt; vH = t; }
            else            { lo = tc + 1; cl = cnt; vL = t; }
            if (cl == 511) {
                float c = 3.4e38f;
                #pragma unroll
                for (int j = 0; j < 16; ++j)
                    c = fminf(c, (s[j] > vL) ? s[j] : 3.4e38f);
                #pragma unroll
                for (int off = 32; off > 0; off >>= 1)
                    c = fminf(c, __shfl_xor(c, off));
                medf = c; found = 1;
            } else if (ch == 512) {
                float c = -3.4e38f;
                #pragma unroll
                for (int j = 0; j < 16; ++j)
                    c = fmaxf(c, (s[j] <= vH) ? s[j] : -3.4e38f);
                #pragma unroll
                for (int off = 32; off > 0; off >>= 1)
                    c = fmaxf(c, __shfl_xor(c, off));
                medf = c; found = 1;
            } else if (lo >= hi) {
                medf = u2f(lo); found = 1;   // heavy ties: code-exact
            } else {
                float tn = t + ((float)(512 - cnt) - 0.5f) * step;
                bool ok = (tn > vL) && (tn < vH);
                if (pass >= 5 && (pass & 1)) ok = false;   // forced bisection
                t = ok ? tn : u2f(lo + ((hi - lo) >> 1));
            }
        }
        if (!found) medf = u2f(lo);

        // ---- phase 2.5: masked exp, f16 round, row-sum, swizzled P writes ----
        float sum = 0.f;
        #pragma unroll
        for (int b = 0; b < 4; ++b) {
            f16x4 hv;
            #pragma unroll
            for (int jj = 0; jj < 4; ++jj) {
                float e = (s[(b << 2) + jj] > medf) ? __expf(s[(b << 2) + jj]) : 0.f;
                _Float16 h = (_Float16)e;
                hv[jj] = h;
                sum += (float)h;
            }
            // cols c = (b<<8) + (lane<<2): octet o = (b<<5)+(lane>>1), half = c&7
            const int o  = (b << 5) + (lane >> 1);
            const int op = o ^ wave;                 // swizzle key = row&7
            *(f16x4*)&P[wave][(op << 3) + ((lane & 1) << 2)] = hv;
        }
        #pragma unroll
        for (int off = 32; off > 0; off >>= 1) sum += __shfl_xor(sum, off);
        if (lane == 0) sums[sb][wave] = sum;
        __syncthreads();   // B3: P + sums visible

        // ---- phase 3: PV via MFMA; A=P (swizzled), B=V registers ----
        f32x4 acc = {0.f, 0.f, 0.f, 0.f};
        const _Float16* Pr = &P[fm & 7][0];
        #pragma unroll
        for (int kb = 0; kb < 4; ++kb) {
            const int o  = (wave << 4) + (kb << 2) + fq;   // octet of row fm
            const int op = o ^ (fm & 7);
            f16x8 a = *(const f16x8*)(Pr + (op << 3));
            acc = __builtin_amdgcn_mfma_f32_16x16x32_f16(a, Vf[kb], acc, 0, 0, 0);
        }
        if (lane < 32) {   // C rows 0-7 live in quads 0-1
            #pragma unroll
            for (int i = 0; i < 4; ++i)
                part[(wave << 7) + (((fq << 2) + i) << 4) + fm] = acc[i];
        }
        __syncthreads();   // B4: partials visible (also: P reads done)

        // ---- reduce 8 partials + store; rotate active waves by chunk ----
        const int rw = (wave - chunk) & 7;
        if (rw < 2) {
            const int t2 = (rw << 6) + lane;
            const int r = t2 >> 4, d = t2 & 15;
            float o = 0.f;
            #pragma unroll
            for (int w = 0; w < 8; ++w) o += part[(w << 7) + t2];
            const float inv = 1.0f / sums[sb][r];
            const int q = qbase + r;
            const int h = head >> 3, bp = head & 7;
            float* dst = Ob + (((size_t)(h >> 1)) << 18)
                            + ((size_t)(((h & 1) << 9) + (q >> 1)) << 8)
                            + ((q & 1) << 7) + (bp << 4) + d;
            *dst = o * inv;
        }
    }
}

// ---------------------------------------------------------------------------
extern "C" void kernel_launch(void* const* d_in, const int* in_sizes, int n_in,
                              void* d_out, int out_size, void* d_ws, size_t ws_size,
                              hipStream_t stream) {
    const float* x  = (const float*)d_in[0];
    const float* y  = (const float*)d_in[1];
    const float* Wq = (const float*)d_in[2];
    const float* bq = (const float*)d_in[3];
    const float* Wk = (const float*)d_in[4];
    const float* bk = (const float*)d_in[5];
    const float* Wv = (const float*)d_in[6];
    const float* bv = (const float*)d_in[7];
    const float* Wo = (const float*)d_in[8];
    const float* bo = (const float*)d_in[9];
    float* out = (float*)d_out;

    float* Q  = (float*)d_ws;
    float* K  = Q + 2097152;
    float* V  = K + 2097152;
    float* AO = V + 2097152;

    gemmQKV<<<dim3(128, 4, 3), dim3(256), 0, stream>>>(x, y, Wq, bq, Wk, bk,
                                                       Wv, bv, Q, K, V);
    attn<<<dim3(128, 6), dim3(512), 0, stream>>>(Q, K, V, AO);
    gemmOut<<<dim3(128, 4), dim3(256), 0, stream>>>(AO, Wo, bo, out);
}

// Round 10
// 342.767 us; speedup vs baseline: 1.0184x; 1.0184x over previous
//
#include <hip/hip_runtime.h>
#include <stdint.h>

// B=8, S=1024, D_MODEL=256, dk=dv=16, 128 pseudo-heads of 1024x16.
// ws layout (floats): Q[2M] | K[2M] | V[2M] | AO[2M] -> 32 MB.

typedef _Float16 f16x8 __attribute__((ext_vector_type(8)));
typedef _Float16 f16x4 __attribute__((ext_vector_type(4)));
typedef _Float16 f16x2 __attribute__((ext_vector_type(2)));
typedef float    f32x4 __attribute__((ext_vector_type(4)));

// ---------------------------------------------------------------------------
// Split-f16 MFMA GEMM (unchanged from R8): C[8192x256] = A @ W + bias.
// ---------------------------------------------------------------------------
__device__ __forceinline__ void gemm_mfma(const float* __restrict__ A,
                                          const float* __restrict__ W,
                                          const float* __restrict__ bias,
                                          float* __restrict__ C)
{
    __shared__ _Float16 Bhi[64][264];
    __shared__ _Float16 Blo[64][264];
    const int tid = threadIdx.x;
    const int m0 = blockIdx.x << 6, n0 = blockIdx.y << 6;

    {
        const int kk = (tid & 127) << 1;
        const int nh = (tid >> 7) << 5;
        const float* w0 = W + (size_t)kk * 256 + n0 + nh;
        const float* w1 = w0 + 256;
        #pragma unroll
        for (int c4 = 0; c4 < 8; ++c4) {
            float4 v0 = *(const float4*)(w0 + (c4 << 2));
            float4 v1 = *(const float4*)(w1 + (c4 << 2));
            const float e0[4] = {v0.x, v0.y, v0.z, v0.w};
            const float e1[4] = {v1.x, v1.y, v1.z, v1.w};
            #pragma unroll
            for (int jj = 0; jj < 4; ++jj) {
                const int n = nh + (c4 << 2) + jj;
                _Float16 h0 = (_Float16)e0[jj];
                _Float16 h1 = (_Float16)e1[jj];
                f16x2 hp; hp[0] = h0; hp[1] = h1;
                f16x2 lp; lp[0] = (_Float16)(e0[jj] - (float)h0);
                          lp[1] = (_Float16)(e1[jj] - (float)h1);
                *(f16x2*)&Bhi[n][kk] = hp;
                *(f16x2*)&Blo[n][kk] = lp;
            }
        }
    }
    __syncthreads();

    const int wv = tid >> 6, lane = tid & 63;
    const int fm = lane & 15, fq = lane >> 4;
    const int arow = m0 + (wv << 4) + fm;

    f32x4 acc[4];
    #pragma unroll
    for (int cb = 0; cb < 4; ++cb) { acc[cb][0]=0.f; acc[cb][1]=0.f; acc[cb][2]=0.f; acc[cb][3]=0.f; }

    #pragma unroll
    for (int kb = 0; kb < 8; ++kb) {
        const float* ap = A + (size_t)arow * 256 + (kb << 5) + (fq << 3);
        float4 a0 = *(const float4*)ap;
        float4 a1 = *(const float4*)(ap + 4);
        const float ae[8] = {a0.x, a0.y, a0.z, a0.w, a1.x, a1.y, a1.z, a1.w};
        f16x8 Ah, Al;
        #pragma unroll
        for (int j = 0; j < 8; ++j) {
            _Float16 h = (_Float16)ae[j];
            Ah[j] = h;
            Al[j] = (_Float16)(ae[j] - (float)h);
        }
        #pragma unroll
        for (int cb = 0; cb < 4; ++cb) {
            f16x8 Bh = *(const f16x8*)&Bhi[(cb << 4) + fm][(kb << 5) + (fq << 3)];
            f16x8 Bl = *(const f16x8*)&Blo[(cb << 4) + fm][(kb << 5) + (fq << 3)];
            acc[cb] = __builtin_amdgcn_mfma_f32_16x16x32_f16(Ah, Bh, acc[cb], 0, 0, 0);
            acc[cb] = __builtin_amdgcn_mfma_f32_16x16x32_f16(Al, Bh, acc[cb], 0, 0, 0);
            acc[cb] = __builtin_amdgcn_mfma_f32_16x16x32_f16(Ah, Bl, acc[cb], 0, 0, 0);
        }
    }

    #pragma unroll
    for (int cb = 0; cb < 4; ++cb) {
        const float bb = bias[n0 + (cb << 4) + fm];
        #pragma unroll
        for (int i = 0; i < 4; ++i)
            C[(size_t)(m0 + (wv << 4) + (fq << 2) + i) * 256
              + n0 + (cb << 4) + fm] = acc[cb][i] + bb;
    }
}

__global__ __attribute__((amdgpu_waves_per_eu(2, 2)))
__launch_bounds__(256) void gemmQKV(
    const float* __restrict__ x, const float* __restrict__ y,
    const float* __restrict__ Wq, const float* __restrict__ bq,
    const float* __restrict__ Wk, const float* __restrict__ bk,
    const float* __restrict__ Wv, const float* __restrict__ bv,
    float* __restrict__ Q, float* __restrict__ K, float* __restrict__ V)
{
    const int z = blockIdx.z;
    const float* A = (z == 0) ? x  : y;
    const float* W = (z == 0) ? Wq : (z == 1) ? Wk : Wv;
    const float* b = (z == 0) ? bq : (z == 1) ? bk : bv;
    float*       C = (z == 0) ? Q  : (z == 1) ? K  : V;
    gemm_mfma(A, W, b, C);
}

__global__ __attribute__((amdgpu_waves_per_eu(2, 2)))
__launch_bounds__(256) void gemmOut(
    const float* __restrict__ A, const float* __restrict__ W,
    const float* __restrict__ b, float* __restrict__ C)
{
    gemm_mfma(A, W, b, C);
}

// ---------------------------------------------------------------------------
// Attention — R8 structure exactly; only occupancy pin + grid changed.
// waves_per_eu(4,4): VGPR budget 128 >= live set (~90) -> NO SPILL (R5-R9 ran
// at VGPR=40 with ~26 MB of scratch writes per dispatch; R9's extra LDS pushed
// spill reloads out of L2: FETCH 27->140 MB, dur +22 us). 2 blocks/CU exact
// with grid (128,4) = 512 blocks, 32 chunks each.
// ---------------------------------------------------------------------------
__device__ __forceinline__ float u2f(unsigned int m) {
    unsigned int x = (m & 0x80000000u) ? (m ^ 0x80000000u) : ~m;
    return __uint_as_float(x);
}
__device__ __forceinline__ unsigned int f2u(float f) {
    unsigned int x = __float_as_uint(f);
    return (x & 0x80000000u) ? ~x : (x | 0x80000000u);
}

__global__ __attribute__((amdgpu_waves_per_eu(4, 4)))
__launch_bounds__(512) void attn(
    const float* __restrict__ Qb, const float* __restrict__ Kb,
    const float* __restrict__ Vb, float* __restrict__ Ob)
{
    __shared__ union {
        float    Ssc[8][1028];     // pad 1028: MFMA C-writes land 32 distinct banks
        _Float16 P[16][1032];
        _Float16 Vt[16][1032];
    } U;
    __shared__ float part[1024];   // [8 waves][8 rows][16 d]
    __shared__ float sums[2][8];

    const int tid  = threadIdx.x;
    const int wave = tid >> 6, lane = tid & 63;
    const int head = blockIdx.x, grp = blockIdx.y;
    const float* Qh = Qb + ((size_t)head << 14);
    const float* Kh = Kb + ((size_t)head << 14);
    const float* Vh = Vb + ((size_t)head << 14);
    const int fm = lane & 15, fq = lane >> 4;

    // ---- stage V transposed (f16) into the union, grab register fragments ----
    for (int i = tid; i < 4096; i += 512) {
        float4 v = ((const float4*)Vh)[i];
        const int k = i >> 2, d0 = (i & 3) << 2;
        U.Vt[d0 + 0][k] = (_Float16)v.x;
        U.Vt[d0 + 1][k] = (_Float16)v.y;
        U.Vt[d0 + 2][k] = (_Float16)v.z;
        U.Vt[d0 + 3][k] = (_Float16)v.w;
    }
    __syncthreads();
    f16x8 Vf[4];
    #pragma unroll
    for (int kb = 0; kb < 4; ++kb)
        Vf[kb] = *(const f16x8*)&U.Vt[fm][(((wave << 2) + kb) << 5) + (fq << 3)];

    // ---- K fragments packed [Bh|Bl] f16x8, K pre-scaled by 1/8 ----
    f16x8 Bp[8];
    #pragma unroll
    for (int kb = 0; kb < 8; ++kb) {
        const int krow = (wave << 7) + (kb << 4) + fm;
        float4 kv = *(const float4*)(Kh + ((size_t)krow << 4) + (fq << 2));
        const float ke[4] = {kv.x * 0.125f, kv.y * 0.125f,
                             kv.z * 0.125f, kv.w * 0.125f};
        #pragma unroll
        for (int j = 0; j < 4; ++j) {
            _Float16 h = (_Float16)ke[j];
            Bp[kb][j]     = h;
            Bp[kb][j + 4] = (_Float16)(ke[j] - (float)h);
        }
    }
    __syncthreads();               // Vf reads done before Ssc overwrites Vt

    const int cstart = grp << 5;
    const int cend   = cstart + 32;

    for (int chunk = cstart; chunk < cend; ++chunk) {
        const int qbase = chunk << 3;
        const int sb = chunk & 1;

        // ---- phase 1: S = Q K^T/8, 2 packed MFMAs per 16-col tile ----
        //   c = mfma32([Ah|Ah],[Bh|Bl]) + mfma32([Al|0],[Bh|Bl])
        f16x8 A1, A2;
        {
            const int arow = qbase + (fm & 7);
            float4 qv = *(const float4*)(Qh + ((size_t)arow << 4) + (fq << 2));
            const float qe[4] = {qv.x, qv.y, qv.z, qv.w};
            #pragma unroll
            for (int j = 0; j < 4; ++j) {
                _Float16 h = (_Float16)qe[j];
                A1[j] = h; A1[j + 4] = h;
                A2[j] = (_Float16)(qe[j] - (float)h);
                A2[j + 4] = (_Float16)0.f;
            }
        }
        #pragma unroll
        for (int kb = 0; kb < 8; ++kb) {
            f32x4 c = {0.f, 0.f, 0.f, 0.f};
            c = __builtin_amdgcn_mfma_f32_16x16x32_f16(A1, Bp[kb], c, 0, 0, 0);
            c = __builtin_amdgcn_mfma_f32_16x16x32_f16(A2, Bp[kb], c, 0, 0, 0);
            if (fq < 2) {
                const int col = (wave << 7) + (kb << 4) + fm;
                #pragma unroll
                for (int i = 0; i < 4; ++i)
                    U.Ssc[(fq << 2) + i][col] = c[i];
            }
        }
        __syncthreads();   // B1: scores visible

        // ---- wave w owns row w; contiguous b128 reads ----
        float s[16];
        #pragma unroll
        for (int b = 0; b < 4; ++b) {
            f32x4 v = *(const f32x4*)&U.Ssc[wave][(b << 8) + (lane << 2)];
            s[(b << 2) + 0] = v.x; s[(b << 2) + 1] = v.y;
            s[(b << 2) + 2] = v.z; s[(b << 2) + 3] = v.w;
        }
        __syncthreads();   // B2: Ssc consumed -> reusable as P

        // ---- phase 2: exact lower median (512th smallest) ----
        float mn = 0.f;
        #pragma unroll
        for (int j = 0; j < 16; ++j) mn += s[j];
        #pragma unroll
        for (int off = 32; off > 0; off >>= 1) mn += __shfl_xor(mn, off);
        mn *= (1.0f / 1024.0f);
        const float step = 0.0012239f;   // sigma~0.5: 0.5*2.5066/1024

        unsigned int lo = 0x00800000u, hi = 0xFF7FFFFFu;
        int cl = 0, ch = 1024;
        float vL = -3.4e38f, vH = 3.4e38f;
        float t = mn, medf = 0.f;
        int found = 0;
        for (int pass = 0; pass < 64 && !found; ++pass) {
            int cnt = 0;
            #pragma unroll
            for (int j = 0; j < 16; ++j)
                cnt += __popcll(__ballot(s[j] <= t));
            const unsigned int tc = f2u(t);
            if (cnt >= 512) { hi = tc; ch = cnt; vH = t; }
            else            { lo = tc + 1; cl = cnt; vL = t; }
            if (cl == 511) {
                float c = 3.4e38f;
                #pragma unroll
                for (int j = 0; j < 16; ++j)
                    c = fminf(c, (s[j] > vL) ? s[j] : 3.4e38f);
                #pragma unroll
                for (int off = 32; off > 0; off >>= 1)
                    c = fminf(c, __shfl_xor(c, off));
                medf = c; found = 1;
            } else if (ch == 512) {
                float c = -3.4e38f;
                #pragma unroll
                for (int j = 0; j < 16; ++j)
                    c = fmaxf(c, (s[j] <= vH) ? s[j] : -3.4e38f);
                #pragma unroll
                for (int off = 32; off > 0; off >>= 1)
                    c = fmaxf(c, __shfl_xor(c, off));
                medf = c; found = 1;
            } else if (lo >= hi) {
                medf = u2f(lo); found = 1;   // heavy ties: code-exact
            } else {
                float tn = t + ((float)(512 - cnt) - 0.5f) * step;
                bool ok = (tn > vL) && (tn < vH);
                if (pass >= 5 && (pass & 1)) ok = false;   // forced bisection
                t = ok ? tn : u2f(lo + ((hi - lo) >> 1));
            }
        }
        if (!found) medf = u2f(lo);

        // ---- phase 2.5: masked exp, f16 round, row-sum, P writes ----
        float sum = 0.f;
        #pragma unroll
        for (int b = 0; b < 4; ++b) {
            f16x4 hv;
            #pragma unroll
            for (int jj = 0; jj < 4; ++jj) {
                float e = (s[(b << 2) + jj] > medf) ? __expf(s[(b << 2) + jj]) : 0.f;
                _Float16 h = (_Float16)e;
                hv[jj] = h;
                sum += (float)h;
            }
            *(f16x4*)&U.P[wave][(b << 8) + (lane << 2)] = hv;
        }
        #pragma unroll
        for (int off = 32; off > 0; off >>= 1) sum += __shfl_xor(sum, off);
        if (lane == 0) sums[sb][wave] = sum;
        __syncthreads();   // B3: P + sums visible

        // ---- phase 3: PV via MFMA; A=P from LDS, B=V from registers ----
        f32x4 acc = {0.f, 0.f, 0.f, 0.f};
        const _Float16* Pr = &U.P[fm][fq << 3];
        #pragma unroll
        for (int kb = 0; kb < 4; ++kb) {
            f16x8 a = *(const f16x8*)(Pr + ((((wave << 2) + kb)) << 5));
            acc = __builtin_amdgcn_mfma_f32_16x16x32_f16(a, Vf[kb], acc, 0, 0, 0);
        }
        if (lane < 32) {   // C rows 0-7 live in quads 0-1
            #pragma unroll
            for (int i = 0; i < 4; ++i)
                part[(wave << 7) + (((fq << 2) + i) << 4) + fm] = acc[i];
        }
        __syncthreads();   // B4: partials visible (also: P reads done)

        // ---- reduce 8 partials + store; rotate active waves by chunk ----
        const int rw = (wave - chunk) & 7;
        if (rw < 2) {
            const int t2 = (rw << 6) + lane;
            const int r = t2 >> 4, d = t2 & 15;
            float o = 0.f;
            #pragma unroll
            for (int w = 0; w < 8; ++w) o += part[(w << 7) + t2];
            const float inv = 1.0f / sums[sb][r];
            const int q = qbase + r;
            const int h = head >> 3, bp = head & 7;
            float* dst = Ob + (((size_t)(h >> 1)) << 18)
                            + ((size_t)(((h & 1) << 9) + (q >> 1)) << 8)
                            + ((q & 1) << 7) + (bp << 4) + d;
            *dst = o * inv;
        }
    }
}

// ---------------------------------------------------------------------------
extern "C" void kernel_launch(void* const* d_in, const int* in_sizes, int n_in,
                              void* d_out, int out_size, void* d_ws, size_t ws_size,
                              hipStream_t stream) {
    const float* x  = (const float*)d_in[0];
    const float* y  = (const float*)d_in[1];
    const float* Wq = (const float*)d_in[2];
    const float* bq = (const float*)d_in[3];
    const float* Wk = (const float*)d_in[4];
    const float* bk = (const float*)d_in[5];
    const float* Wv = (const float*)d_in[6];
    const float* bv = (const float*)d_in[7];
    const float* Wo = (const float*)d_in[8];
    const float* bo = (const float*)d_in[9];
    float* out = (float*)d_out;

    float* Q  = (float*)d_ws;
    float* K  = Q + 2097152;
    float* V  = K + 2097152;
    float* AO = V + 2097152;

    gemmQKV<<<dim3(128, 4, 3), dim3(256), 0, stream>>>(x, y, Wq, bq, Wk, bk,
                                                       Wv, bv, Q, K, V);
    attn<<<dim3(128, 4), dim3(512), 0, stream>>>(Q, K, V, AO);
    gemmOut<<<dim3(128, 4), dim3(256), 0, stream>>>(AO, Wo, bo, out);
}

// Round 11
// 338.869 us; speedup vs baseline: 1.0302x; 1.0115x over previous
//
#include <hip/hip_runtime.h>
#include <stdint.h>

// B=8, S=1024, D_MODEL=256, dk=dv=16, 128 pseudo-heads of 1024x16.
// ws layout (floats): Q[2M] | K[2M] | V[2M] | AO[2M] -> 32 MB.

typedef _Float16 f16x8 __attribute__((ext_vector_type(8)));
typedef _Float16 f16x4 __attribute__((ext_vector_type(4)));
typedef _Float16 f16x2 __attribute__((ext_vector_type(2)));
typedef float    f32x4 __attribute__((ext_vector_type(4)));

// ---------------------------------------------------------------------------
// Split-f16 MFMA GEMM (unchanged from R8): C[8192x256] = A @ W + bias.
// ---------------------------------------------------------------------------
__device__ __forceinline__ void gemm_mfma(const float* __restrict__ A,
                                          const float* __restrict__ W,
                                          const float* __restrict__ bias,
                                          float* __restrict__ C)
{
    __shared__ _Float16 Bhi[64][264];
    __shared__ _Float16 Blo[64][264];
    const int tid = threadIdx.x;
    const int m0 = blockIdx.x << 6, n0 = blockIdx.y << 6;

    {
        const int kk = (tid & 127) << 1;
        const int nh = (tid >> 7) << 5;
        const float* w0 = W + (size_t)kk * 256 + n0 + nh;
        const float* w1 = w0 + 256;
        #pragma unroll
        for (int c4 = 0; c4 < 8; ++c4) {
            float4 v0 = *(const float4*)(w0 + (c4 << 2));
            float4 v1 = *(const float4*)(w1 + (c4 << 2));
            const float e0[4] = {v0.x, v0.y, v0.z, v0.w};
            const float e1[4] = {v1.x, v1.y, v1.z, v1.w};
            #pragma unroll
            for (int jj = 0; jj < 4; ++jj) {
                const int n = nh + (c4 << 2) + jj;
                _Float16 h0 = (_Float16)e0[jj];
                _Float16 h1 = (_Float16)e1[jj];
                f16x2 hp; hp[0] = h0; hp[1] = h1;
                f16x2 lp; lp[0] = (_Float16)(e0[jj] - (float)h0);
                          lp[1] = (_Float16)(e1[jj] - (float)h1);
                *(f16x2*)&Bhi[n][kk] = hp;
                *(f16x2*)&Blo[n][kk] = lp;
            }
        }
    }
    __syncthreads();

    const int wv = tid >> 6, lane = tid & 63;
    const int fm = lane & 15, fq = lane >> 4;
    const int arow = m0 + (wv << 4) + fm;

    f32x4 acc[4];
    #pragma unroll
    for (int cb = 0; cb < 4; ++cb) { acc[cb][0]=0.f; acc[cb][1]=0.f; acc[cb][2]=0.f; acc[cb][3]=0.f; }

    #pragma unroll
    for (int kb = 0; kb < 8; ++kb) {
        const float* ap = A + (size_t)arow * 256 + (kb << 5) + (fq << 3);
        float4 a0 = *(const float4*)ap;
        float4 a1 = *(const float4*)(ap + 4);
        const float ae[8] = {a0.x, a0.y, a0.z, a0.w, a1.x, a1.y, a1.z, a1.w};
        f16x8 Ah, Al;
        #pragma unroll
        for (int j = 0; j < 8; ++j) {
            _Float16 h = (_Float16)ae[j];
            Ah[j] = h;
            Al[j] = (_Float16)(ae[j] - (float)h);
        }
        #pragma unroll
        for (int cb = 0; cb < 4; ++cb) {
            f16x8 Bh = *(const f16x8*)&Bhi[(cb << 4) + fm][(kb << 5) + (fq << 3)];
            f16x8 Bl = *(const f16x8*)&Blo[(cb << 4) + fm][(kb << 5) + (fq << 3)];
            acc[cb] = __builtin_amdgcn_mfma_f32_16x16x32_f16(Ah, Bh, acc[cb], 0, 0, 0);
            acc[cb] = __builtin_amdgcn_mfma_f32_16x16x32_f16(Al, Bh, acc[cb], 0, 0, 0);
            acc[cb] = __builtin_amdgcn_mfma_f32_16x16x32_f16(Ah, Bl, acc[cb], 0, 0, 0);
        }
    }

    #pragma unroll
    for (int cb = 0; cb < 4; ++cb) {
        const float bb = bias[n0 + (cb << 4) + fm];
        #pragma unroll
        for (int i = 0; i < 4; ++i)
            C[(size_t)(m0 + (wv << 4) + (fq << 2) + i) * 256
              + n0 + (cb << 4) + fm] = acc[cb][i] + bb;
    }
}

__global__ __attribute__((amdgpu_waves_per_eu(2, 2)))
__launch_bounds__(256) void gemmQKV(
    const float* __restrict__ x, const float* __restrict__ y,
    const float* __restrict__ Wq, const float* __restrict__ bq,
    const float* __restrict__ Wk, const float* __restrict__ bk,
    const float* __restrict__ Wv, const float* __restrict__ bv,
    float* __restrict__ Q, float* __restrict__ K, float* __restrict__ V)
{
    const int z = blockIdx.z;
    const float* A = (z == 0) ? x  : y;
    const float* W = (z == 0) ? Wq : (z == 1) ? Wk : Wv;
    const float* b = (z == 0) ? bq : (z == 1) ? bk : bv;
    float*       C = (z == 0) ? Q  : (z == 1) ? K  : V;
    gemm_mfma(A, W, b, C);
}

__global__ __attribute__((amdgpu_waves_per_eu(2, 2)))
__launch_bounds__(256) void gemmOut(
    const float* __restrict__ A, const float* __restrict__ W,
    const float* __restrict__ b, float* __restrict__ C)
{
    gemm_mfma(A, W, b, C);
}

// ---------------------------------------------------------------------------
// Attention — R8 structure at 3 blocks/CU, WITHOUT the register spill:
// K fragments are no longer persistent (32 VGPRs freed). Each chunk reloads
// the wave's 8 K-tiles from global (L2/L3-resident, 8 coalesced dwordx4/lane)
// and re-does the hi/lo split. Peak live set now ~70 < the ~85-VGPR budget at
// waves_per_eu(6,6) -> no scratch traffic (R8 had ~26 MB/dispatch), while
// keeping 24 waves/CU latency hiding (R10 showed 16 waves costs ~16 us).
// ---------------------------------------------------------------------------
__device__ __forceinline__ float u2f(unsigned int m) {
    unsigned int x = (m & 0x80000000u) ? (m ^ 0x80000000u) : ~m;
    return __uint_as_float(x);
}
__device__ __forceinline__ unsigned int f2u(float f) {
    unsigned int x = __float_as_uint(f);
    return (x & 0x80000000u) ? ~x : (x | 0x80000000u);
}

__global__ __attribute__((amdgpu_waves_per_eu(6, 6)))
__launch_bounds__(512) void attn(
    const float* __restrict__ Qb, const float* __restrict__ Kb,
    const float* __restrict__ Vb, float* __restrict__ Ob)
{
    __shared__ union {
        float    Ssc[8][1028];     // pad 1028: MFMA C-writes land 32 distinct banks
        _Float16 P[16][1032];
        _Float16 Vt[16][1032];
    } U;
    __shared__ float part[1024];   // [8 waves][8 rows][16 d]
    __shared__ float sums[2][8];

    const int tid  = threadIdx.x;
    const int wave = tid >> 6, lane = tid & 63;
    const int head = blockIdx.x, grp = blockIdx.y;
    const float* Qh = Qb + ((size_t)head << 14);
    const float* Kh = Kb + ((size_t)head << 14);
    const float* Vh = Vb + ((size_t)head << 14);
    const int fm = lane & 15, fq = lane >> 4;

    // ---- stage V transposed (f16) into the union, grab register fragments ----
    for (int i = tid; i < 4096; i += 512) {
        float4 v = ((const float4*)Vh)[i];
        const int k = i >> 2, d0 = (i & 3) << 2;
        U.Vt[d0 + 0][k] = (_Float16)v.x;
        U.Vt[d0 + 1][k] = (_Float16)v.y;
        U.Vt[d0 + 2][k] = (_Float16)v.z;
        U.Vt[d0 + 3][k] = (_Float16)v.w;
    }
    __syncthreads();
    f16x8 Vf[4];
    #pragma unroll
    for (int kb = 0; kb < 4; ++kb)
        Vf[kb] = *(const f16x8*)&U.Vt[fm][(((wave << 2) + kb) << 5) + (fq << 3)];
    __syncthreads();               // Vf reads done before Ssc overwrites Vt

    const int cstart = (grp * 128) / 6;
    const int cend   = ((grp + 1) * 128) / 6;

    for (int chunk = cstart; chunk < cend; ++chunk) {
        const int qbase = chunk << 3;
        const int sb = chunk & 1;

        // ---- phase 1: S = Q K^T/8, 2 packed MFMAs per 16-col tile ----
        //   c = mfma32([Ah|Ah],[Bh|Bl]) + mfma32([Al|0],[Bh|Bl])
        // K tiles loaded fresh each chunk (transient regs, not persistent).
        float4 kvs[8];
        #pragma unroll
        for (int kb = 0; kb < 8; ++kb) {
            const int krow = (wave << 7) + (kb << 4) + fm;
            kvs[kb] = *(const float4*)(Kh + ((size_t)krow << 4) + (fq << 2));
        }
        f16x8 A1, A2;
        {
            const int arow = qbase + (fm & 7);
            float4 qv = *(const float4*)(Qh + ((size_t)arow << 4) + (fq << 2));
            const float qe[4] = {qv.x, qv.y, qv.z, qv.w};
            #pragma unroll
            for (int j = 0; j < 4; ++j) {
                _Float16 h = (_Float16)qe[j];
                A1[j] = h; A1[j + 4] = h;
                A2[j] = (_Float16)(qe[j] - (float)h);
                A2[j + 4] = (_Float16)0.f;
            }
        }
        #pragma unroll
        for (int kb = 0; kb < 8; ++kb) {
            const float ke[4] = {kvs[kb].x * 0.125f, kvs[kb].y * 0.125f,
                                 kvs[kb].z * 0.125f, kvs[kb].w * 0.125f};
            f16x8 Bp;
            #pragma unroll
            for (int j = 0; j < 4; ++j) {
                _Float16 h = (_Float16)ke[j];
                Bp[j]     = h;
                Bp[j + 4] = (_Float16)(ke[j] - (float)h);
            }
            f32x4 c = {0.f, 0.f, 0.f, 0.f};
            c = __builtin_amdgcn_mfma_f32_16x16x32_f16(A1, Bp, c, 0, 0, 0);
            c = __builtin_amdgcn_mfma_f32_16x16x32_f16(A2, Bp, c, 0, 0, 0);
            if (fq < 2) {
                const int col = (wave << 7) + (kb << 4) + fm;
                #pragma unroll
                for (int i = 0; i < 4; ++i)
                    U.Ssc[(fq << 2) + i][col] = c[i];
            }
        }
        __syncthreads();   // B1: scores visible

        // ---- wave w owns row w; contiguous b128 reads ----
        float s[16];
        #pragma unroll
        for (int b = 0; b < 4; ++b) {
            f32x4 v = *(const f32x4*)&U.Ssc[wave][(b << 8) + (lane << 2)];
            s[(b << 2) + 0] = v.x; s[(b << 2) + 1] = v.y;
            s[(b << 2) + 2] = v.z; s[(b << 2) + 3] = v.w;
        }
        __syncthreads();   // B2: Ssc consumed -> reusable as P

        // ---- phase 2: exact lower median (512th smallest) ----
        float mn = 0.f;
        #pragma unroll
        for (int j = 0; j < 16; ++j) mn += s[j];
        #pragma unroll
        for (int off = 32; off > 0; off >>= 1) mn += __shfl_xor(mn, off);
        mn *= (1.0f / 1024.0f);
        const float step = 0.0012239f;   // sigma~0.5: 0.5*2.5066/1024

        unsigned int lo = 0x00800000u, hi = 0xFF7FFFFFu;
        int cl = 0, ch = 1024;
        float vL = -3.4e38f, vH = 3.4e38f;
        float t = mn, medf = 0.f;
        int found = 0;
        for (int pass = 0; pass < 64 && !found; ++pass) {
            int cnt = 0;
            #pragma unroll
            for (int j = 0; j < 16; ++j)
                cnt += __popcll(__ballot(s[j] <= t));
            const unsigned int tc = f2u(t);
            if (cnt >= 512) { hi = tc; ch = cnt; vH = t; }
            else            { lo = tc + 1; cl = cnt; vL = t; }
            if (cl == 511) {
                float c = 3.4e38f;
                #pragma unroll
                for (int j = 0; j < 16; ++j)
                    c = fminf(c, (s[j] > vL) ? s[j] : 3.4e38f);
                #pragma unroll
                for (int off = 32; off > 0; off >>= 1)
                    c = fminf(c, __shfl_xor(c, off));
                medf = c; found = 1;
            } else if (ch == 512) {
                float c = -3.4e38f;
                #pragma unroll
                for (int j = 0; j < 16; ++j)
                    c = fmaxf(c, (s[j] <= vH) ? s[j] : -3.4e38f);
                #pragma unroll
                for (int off = 32; off > 0; off >>= 1)
                    c = fmaxf(c, __shfl_xor(c, off));
                medf = c; found = 1;
            } else if (lo >= hi) {
                medf = u2f(lo); found = 1;   // heavy ties: code-exact
            } else {
                float tn = t + ((float)(512 - cnt) - 0.5f) * step;
                bool ok = (tn > vL) && (tn < vH);
                if (pass >= 5 && (pass & 1)) ok = false;   // forced bisection
                t = ok ? tn : u2f(lo + ((hi - lo) >> 1));
            }
        }
        if (!found) medf = u2f(lo);

        // ---- phase 2.5: masked exp, f16 round, row-sum, P writes ----
        float sum = 0.f;
        #pragma unroll
        for (int b = 0; b < 4; ++b) {
            f16x4 hv;
            #pragma unroll
            for (int jj = 0; jj < 4; ++jj) {
                float e = (s[(b << 2) + jj] > medf) ? __expf(s[(b << 2) + jj]) : 0.f;
                _Float16 h = (_Float16)e;
                hv[jj] = h;
                sum += (float)h;
            }
            *(f16x4*)&U.P[wave][(b << 8) + (lane << 2)] = hv;
        }
        #pragma unroll
        for (int off = 32; off > 0; off >>= 1) sum += __shfl_xor(sum, off);
        if (lane == 0) sums[sb][wave] = sum;
        __syncthreads();   // B3: P + sums visible

        // ---- phase 3: PV via MFMA; A=P from LDS, B=V from registers ----
        f32x4 acc = {0.f, 0.f, 0.f, 0.f};
        const _Float16* Pr = &U.P[fm][fq << 3];
        #pragma unroll
        for (int kb = 0; kb < 4; ++kb) {
            f16x8 a = *(const f16x8*)(Pr + ((((wave << 2) + kb)) << 5));
            acc = __builtin_amdgcn_mfma_f32_16x16x32_f16(a, Vf[kb], acc, 0, 0, 0);
        }
        if (lane < 32) {   // C rows 0-7 live in quads 0-1
            #pragma unroll
            for (int i = 0; i < 4; ++i)
                part[(wave << 7) + (((fq << 2) + i) << 4) + fm] = acc[i];
        }
        __syncthreads();   // B4: partials visible (also: P reads done)

        // ---- reduce 8 partials + store; rotate active waves by chunk ----
        const int rw = (wave - chunk) & 7;
        if (rw < 2) {
            const int t2 = (rw << 6) + lane;
            const int r = t2 >> 4, d = t2 & 15;
            float o = 0.f;
            #pragma unroll
            for (int w = 0; w < 8; ++w) o += part[(w << 7) + t2];
            const float inv = 1.0f / sums[sb][r];
            const int q = qbase + r;
            const int h = head >> 3, bp = head & 7;
            float* dst = Ob + (((size_t)(h >> 1)) << 18)
                            + ((size_t)(((h & 1) << 9) + (q >> 1)) << 8)
                            + ((q & 1) << 7) + (bp << 4) + d;
            *dst = o * inv;
        }
    }
}

// ---------------------------------------------------------------------------
extern "C" void kernel_launch(void* const* d_in, const int* in_sizes, int n_in,
                              void* d_out, int out_size, void* d_ws, size_t ws_size,
                              hipStream_t stream) {
    const float* x  = (const float*)d_in[0];
    const float* y  = (const float*)d_in[1];
    const float* Wq = (const float*)d_in[2];
    const float* bq = (const float*)d_in[3];
    const float* Wk = (const float*)d_in[4];
    const float* bk = (const float*)d_in[5];
    const float* Wv = (const float*)d_in[6];
    const float* bv = (const float*)d_in[7];
    const float* Wo = (const float*)d_in[8];
    const float* bo = (const float*)d_in[9];
    float* out = (float*)d_out;

    float* Q  = (float*)d_ws;
    float* K  = Q + 2097152;
    float* V  = K + 2097152;
    float* AO = V + 2097152;

    gemmQKV<<<dim3(128, 4, 3), dim3(256), 0, stream>>>(x, y, Wq, bq, Wk, bk,
                                                       Wv, bv, Q, K, V);
    attn<<<dim3(128, 6), dim3(512), 0, stream>>>(Q, K, V, AO);
    gemmOut<<<dim3(128, 4), dim3(256), 0, stream>>>(AO, Wo, bo, out);
}

// Round 12
// 321.823 us; speedup vs baseline: 1.0847x; 1.0530x over previous
//
#include <hip/hip_runtime.h>
#include <stdint.h>

// B=8, S=1024, D_MODEL=256, dk=dv=16, 128 pseudo-heads of 1024x16.
// ws layout (floats): Q[2M] | K[2M] | V[2M] | AO[2M] -> 32 MB.

typedef _Float16 f16x8 __attribute__((ext_vector_type(8)));
typedef _Float16 f16x4 __attribute__((ext_vector_type(4)));
typedef _Float16 f16x2 __attribute__((ext_vector_type(2)));
typedef float    f32x4 __attribute__((ext_vector_type(4)));

// ---------------------------------------------------------------------------
// Split-f16 MFMA GEMM (unchanged from R8): C[8192x256] = A @ W + bias.
// ---------------------------------------------------------------------------
__device__ __forceinline__ void gemm_mfma(const float* __restrict__ A,
                                          const float* __restrict__ W,
                                          const float* __restrict__ bias,
                                          float* __restrict__ C)
{
    __shared__ _Float16 Bhi[64][264];
    __shared__ _Float16 Blo[64][264];
    const int tid = threadIdx.x;
    const int m0 = blockIdx.x << 6, n0 = blockIdx.y << 6;

    {
        const int kk = (tid & 127) << 1;
        const int nh = (tid >> 7) << 5;
        const float* w0 = W + (size_t)kk * 256 + n0 + nh;
        const float* w1 = w0 + 256;
        #pragma unroll
        for (int c4 = 0; c4 < 8; ++c4) {
            float4 v0 = *(const float4*)(w0 + (c4 << 2));
            float4 v1 = *(const float4*)(w1 + (c4 << 2));
            const float e0[4] = {v0.x, v0.y, v0.z, v0.w};
            const float e1[4] = {v1.x, v1.y, v1.z, v1.w};
            #pragma unroll
            for (int jj = 0; jj < 4; ++jj) {
                const int n = nh + (c4 << 2) + jj;
                _Float16 h0 = (_Float16)e0[jj];
                _Float16 h1 = (_Float16)e1[jj];
                f16x2 hp; hp[0] = h0; hp[1] = h1;
                f16x2 lp; lp[0] = (_Float16)(e0[jj] - (float)h0);
                          lp[1] = (_Float16)(e1[jj] - (float)h1);
                *(f16x2*)&Bhi[n][kk] = hp;
                *(f16x2*)&Blo[n][kk] = lp;
            }
        }
    }
    __syncthreads();

    const int wv = tid >> 6, lane = tid & 63;
    const int fm = lane & 15, fq = lane >> 4;
    const int arow = m0 + (wv << 4) + fm;

    f32x4 acc[4];
    #pragma unroll
    for (int cb = 0; cb < 4; ++cb) { acc[cb][0]=0.f; acc[cb][1]=0.f; acc[cb][2]=0.f; acc[cb][3]=0.f; }

    #pragma unroll
    for (int kb = 0; kb < 8; ++kb) {
        const float* ap = A + (size_t)arow * 256 + (kb << 5) + (fq << 3);
        float4 a0 = *(const float4*)ap;
        float4 a1 = *(const float4*)(ap + 4);
        const float ae[8] = {a0.x, a0.y, a0.z, a0.w, a1.x, a1.y, a1.z, a1.w};
        f16x8 Ah, Al;
        #pragma unroll
        for (int j = 0; j < 8; ++j) {
            _Float16 h = (_Float16)ae[j];
            Ah[j] = h;
            Al[j] = (_Float16)(ae[j] - (float)h);
        }
        #pragma unroll
        for (int cb = 0; cb < 4; ++cb) {
            f16x8 Bh = *(const f16x8*)&Bhi[(cb << 4) + fm][(kb << 5) + (fq << 3)];
            f16x8 Bl = *(const f16x8*)&Blo[(cb << 4) + fm][(kb << 5) + (fq << 3)];
            acc[cb] = __builtin_amdgcn_mfma_f32_16x16x32_f16(Ah, Bh, acc[cb], 0, 0, 0);
            acc[cb] = __builtin_amdgcn_mfma_f32_16x16x32_f16(Al, Bh, acc[cb], 0, 0, 0);
            acc[cb] = __builtin_amdgcn_mfma_f32_16x16x32_f16(Ah, Bl, acc[cb], 0, 0, 0);
        }
    }

    #pragma unroll
    for (int cb = 0; cb < 4; ++cb) {
        const float bb = bias[n0 + (cb << 4) + fm];
        #pragma unroll
        for (int i = 0; i < 4; ++i)
            C[(size_t)(m0 + (wv << 4) + (fq << 2) + i) * 256
              + n0 + (cb << 4) + fm] = acc[cb][i] + bb;
    }
}

__global__ __attribute__((amdgpu_waves_per_eu(2, 2)))
__launch_bounds__(256) void gemmQKV(
    const float* __restrict__ x, const float* __restrict__ y,
    const float* __restrict__ Wq, const float* __restrict__ bq,
    const float* __restrict__ Wk, const float* __restrict__ bk,
    const float* __restrict__ Wv, const float* __restrict__ bv,
    float* __restrict__ Q, float* __restrict__ K, float* __restrict__ V)
{
    const int z = blockIdx.z;
    const float* A = (z == 0) ? x  : y;
    const float* W = (z == 0) ? Wq : (z == 1) ? Wk : Wv;
    const float* b = (z == 0) ? bq : (z == 1) ? bk : bv;
    float*       C = (z == 0) ? Q  : (z == 1) ? K  : V;
    gemm_mfma(A, W, b, C);
}

__global__ __attribute__((amdgpu_waves_per_eu(2, 2)))
__launch_bounds__(256) void gemmOut(
    const float* __restrict__ A, const float* __restrict__ W,
    const float* __restrict__ b, float* __restrict__ C)
{
    gemm_mfma(A, W, b, C);
}

// ---------------------------------------------------------------------------
// Attention — R8 base (best: 228 us). R12 deltas:
//  (1) per-row sigma (fused sum/sumsq butterfly) -> Newton probes land +-3
//  (2) exact-exit widened to cnt in {510..513} via dup-safe rank extraction
//  (3) B2 barrier deleted: P row w lives inside the Ssc row w the wave just
//      consumed (intra-wave DS ordering makes read-then-overwrite safe)
// ---------------------------------------------------------------------------
__device__ __forceinline__ float u2f(unsigned int m) {
    unsigned int x = (m & 0x80000000u) ? (m ^ 0x80000000u) : ~m;
    return __uint_as_float(x);
}
__device__ __forceinline__ unsigned int f2u(float f) {
    unsigned int x = __float_as_uint(f);
    return (x & 0x80000000u) ? ~x : (x | 0x80000000u);
}

__global__ __attribute__((amdgpu_waves_per_eu(6, 6)))
__launch_bounds__(512) void attn(
    const float* __restrict__ Qb, const float* __restrict__ Kb,
    const float* __restrict__ Vb, float* __restrict__ Ob)
{
    __shared__ union {
        float    Ssc[8][1028];     // pad 1028: phase-1 C-writes hit 32 banks
        _Float16 Vt[16][1032];     // V staging (pre-loop only)
    } U;
    __shared__ float part[1024];   // [8 waves][8 rows][16 d]
    __shared__ float sums[2][8];

    const int tid  = threadIdx.x;
    const int wave = tid >> 6, lane = tid & 63;
    const int head = blockIdx.x, grp = blockIdx.y;
    const float* Qh = Qb + ((size_t)head << 14);
    const float* Kh = Kb + ((size_t)head << 14);
    const float* Vh = Vb + ((size_t)head << 14);
    const int fm = lane & 15, fq = lane >> 4;

    // ---- stage V transposed (f16), grab register fragments ----
    for (int i = tid; i < 4096; i += 512) {
        float4 v = ((const float4*)Vh)[i];
        const int k = i >> 2, d0 = (i & 3) << 2;
        U.Vt[d0 + 0][k] = (_Float16)v.x;
        U.Vt[d0 + 1][k] = (_Float16)v.y;
        U.Vt[d0 + 2][k] = (_Float16)v.z;
        U.Vt[d0 + 3][k] = (_Float16)v.w;
    }
    __syncthreads();
    f16x8 Vf[4];
    #pragma unroll
    for (int kb = 0; kb < 4; ++kb)
        Vf[kb] = *(const f16x8*)&U.Vt[fm][(((wave << 2) + kb) << 5) + (fq << 3)];

    // ---- persistent K fragments packed [Bh|Bl], K pre-scaled by 1/8 ----
    f16x8 Bp[8];
    #pragma unroll
    for (int kb = 0; kb < 8; ++kb) {
        const int krow = (wave << 7) + (kb << 4) + fm;
        float4 kv = *(const float4*)(Kh + ((size_t)krow << 4) + (fq << 2));
        const float ke[4] = {kv.x * 0.125f, kv.y * 0.125f,
                             kv.z * 0.125f, kv.w * 0.125f};
        #pragma unroll
        for (int j = 0; j < 4; ++j) {
            _Float16 h = (_Float16)ke[j];
            Bp[kb][j]     = h;
            Bp[kb][j + 4] = (_Float16)(ke[j] - (float)h);
        }
    }
    __syncthreads();               // Vf reads done before Ssc overwrites Vt

    const int cstart = (grp * 128) / 6;
    const int cend   = ((grp + 1) * 128) / 6;

    for (int chunk = cstart; chunk < cend; ++chunk) {
        const int qbase = chunk << 3;
        const int sb = chunk & 1;

        // ---- phase 1: S = Q K^T/8, 2 packed MFMAs per 16-col tile ----
        f16x8 A1, A2;
        {
            const int arow = qbase + (fm & 7);
            float4 qv = *(const float4*)(Qh + ((size_t)arow << 4) + (fq << 2));
            const float qe[4] = {qv.x, qv.y, qv.z, qv.w};
            #pragma unroll
            for (int j = 0; j < 4; ++j) {
                _Float16 h = (_Float16)qe[j];
                A1[j] = h; A1[j + 4] = h;
                A2[j] = (_Float16)(qe[j] - (float)h);
                A2[j + 4] = (_Float16)0.f;
            }
        }
        #pragma unroll
        for (int kb = 0; kb < 8; ++kb) {
            f32x4 c = {0.f, 0.f, 0.f, 0.f};
            c = __builtin_amdgcn_mfma_f32_16x16x32_f16(A1, Bp[kb], c, 0, 0, 0);
            c = __builtin_amdgcn_mfma_f32_16x16x32_f16(A2, Bp[kb], c, 0, 0, 0);
            if (fq < 2) {
                const int col = (wave << 7) + (kb << 4) + fm;
                #pragma unroll
                for (int i = 0; i < 4; ++i)
                    U.Ssc[(fq << 2) + i][col] = c[i];
            }
        }
        __syncthreads();   // B1: scores visible

        // ---- wave w owns row w; contiguous b128 reads ----
        float s[16];
        #pragma unroll
        for (int b = 0; b < 4; ++b) {
            f32x4 v = *(const f32x4*)&U.Ssc[wave][(b << 8) + (lane << 2)];
            s[(b << 2) + 0] = v.x; s[(b << 2) + 1] = v.y;
            s[(b << 2) + 2] = v.z; s[(b << 2) + 3] = v.w;
        }
        // (B2 deleted: P row w is written into Ssc row w, which only this
        //  wave has consumed; intra-wave DS ops are in-order.)

        // ---- phase 2: exact lower median (512th smallest) ----
        // fused mean + sumsq butterfly -> per-row sigma for Newton stepping
        float mn = 0.f, sq = 0.f;
        #pragma unroll
        for (int j = 0; j < 16; ++j) { mn += s[j]; sq += s[j] * s[j]; }
        #pragma unroll
        for (int off = 32; off > 0; off >>= 1) {
            mn += __shfl_xor(mn, off);
            sq += __shfl_xor(sq, off);
        }
        mn *= (1.0f / 1024.0f);
        const float var  = fmaxf(sq * (1.0f / 1024.0f) - mn * mn, 1e-12f);
        const float step = __builtin_sqrtf(var) * 0.0024479f; // sigma*sqrt(2pi)/1024

        unsigned int lo = 0x00800000u, hi = 0xFF7FFFFFu;
        int cl = 0, ch = 1024;
        float vL = -3.4e38f, vH = 3.4e38f;
        float t = mn, medf = 0.f;
        int found = 0;
        for (int pass = 0; pass < 64 && !found; ++pass) {
            int cnt = 0;
            #pragma unroll
            for (int j = 0; j < 16; ++j)
                cnt += __popcll(__ballot(s[j] <= t));
            const unsigned int tc = f2u(t);
            if (cnt >= 512) { hi = tc; ch = cnt; vH = t; }
            else            { lo = tc + 1; cl = cnt; vL = t; }

            if (cl == 511) {               // 512th = min{s > vL}
                float c = 3.4e38f;
                #pragma unroll
                for (int j = 0; j < 16; ++j)
                    c = fminf(c, (s[j] > vL) ? s[j] : 3.4e38f);
                #pragma unroll
                for (int off = 32; off > 0; off >>= 1)
                    c = fminf(c, __shfl_xor(c, off));
                medf = c; found = 1;
            } else if (ch == 512) {        // 512th = max{s <= vH}
                float c = -3.4e38f;
                #pragma unroll
                for (int j = 0; j < 16; ++j)
                    c = fmaxf(c, (s[j] <= vH) ? s[j] : -3.4e38f);
                #pragma unroll
                for (int off = 32; off > 0; off >>= 1)
                    c = fmaxf(c, __shfl_xor(c, off));
                medf = c; found = 1;
            } else if (cl == 510) {
                // m1 = 511th = min{s > vL}; dup-safe step to 512th
                float m1 = 3.4e38f;
                #pragma unroll
                for (int j = 0; j < 16; ++j)
                    m1 = fminf(m1, (s[j] > vL) ? s[j] : 3.4e38f);
                #pragma unroll
                for (int off = 32; off > 0; off >>= 1)
                    m1 = fminf(m1, __shfl_xor(m1, off));
                int c1 = 0;
                #pragma unroll
                for (int j = 0; j < 16; ++j)
                    c1 += __popcll(__ballot(s[j] <= m1));
                if (c1 >= 512) { medf = m1; }
                else {
                    float c2 = 3.4e38f;
                    #pragma unroll
                    for (int j = 0; j < 16; ++j)
                        c2 = fminf(c2, (s[j] > m1) ? s[j] : 3.4e38f);
                    #pragma unroll
                    for (int off = 32; off > 0; off >>= 1)
                        c2 = fminf(c2, __shfl_xor(c2, off));
                    medf = c2;
                }
                found = 1;
            } else if (ch == 513) {
                // m1 = 513th = max{s <= vH}; dup-safe step back to 512th
                float m1 = -3.4e38f;
                #pragma unroll
                for (int j = 0; j < 16; ++j)
                    m1 = fmaxf(m1, (s[j] <= vH) ? s[j] : -3.4e38f);
                #pragma unroll
                for (int off = 32; off > 0; off >>= 1)
                    m1 = fmaxf(m1, __shfl_xor(m1, off));
                int c1 = 0;
                #pragma unroll
                for (int j = 0; j < 16; ++j)
                    c1 += __popcll(__ballot(s[j] < m1));
                if (c1 <= 511) { medf = m1; }
                else {
                    float c2 = -3.4e38f;
                    #pragma unroll
                    for (int j = 0; j < 16; ++j)
                        c2 = fmaxf(c2, (s[j] < m1) ? s[j] : -3.4e38f);
                    #pragma unroll
                    for (int off = 32; off > 0; off >>= 1)
                        c2 = fmaxf(c2, __shfl_xor(c2, off));
                    medf = c2;
                }
                found = 1;
            } else if (lo >= hi) {
                medf = u2f(lo); found = 1;   // heavy ties: code-exact
            } else {
                float tn = t + (511.5f - (float)cnt) * step;
                bool ok = (tn > vL) && (tn < vH);
                if (pass >= 5 && (pass & 1)) ok = false;   // forced bisection
                t = ok ? tn : u2f(lo + ((hi - lo) >> 1));
            }
        }
        if (!found) medf = u2f(lo);

        // ---- phase 2.5: masked exp, f16 round, row-sum, P into own Ssc row ----
        _Float16* Pw = (_Float16*)&U.Ssc[wave][0];
        float sum = 0.f;
        #pragma unroll
        for (int b = 0; b < 4; ++b) {
            f16x4 hv;
            #pragma unroll
            for (int jj = 0; jj < 4; ++jj) {
                float e = (s[(b << 2) + jj] > medf) ? __expf(s[(b << 2) + jj]) : 0.f;
                _Float16 h = (_Float16)e;
                hv[jj] = h;
                sum += (float)h;
            }
            *(f16x4*)&Pw[(b << 8) + (lane << 2)] = hv;
        }
        #pragma unroll
        for (int off = 32; off > 0; off >>= 1) sum += __shfl_xor(sum, off);
        if (lane == 0) sums[sb][wave] = sum;
        __syncthreads();   // B3: P + sums visible

        // ---- phase 3: PV via MFMA; A=P rows (dup fm&7), B=V registers ----
        f32x4 acc = {0.f, 0.f, 0.f, 0.f};
        const _Float16* Pr = (const _Float16*)&U.Ssc[fm & 7][0] + (fq << 3);
        #pragma unroll
        for (int kb = 0; kb < 4; ++kb) {
            f16x8 a = *(const f16x8*)(Pr + ((((wave << 2) + kb)) << 5));
            acc = __builtin_amdgcn_mfma_f32_16x16x32_f16(a, Vf[kb], acc, 0, 0, 0);
        }
        if (lane < 32) {   // C rows 0-7 live in quads 0-1
            #pragma unroll
            for (int i = 0; i < 4; ++i)
                part[(wave << 7) + (((fq << 2) + i) << 4) + fm] = acc[i];
        }
        __syncthreads();   // B4: partials visible (also: P reads done)

        // ---- reduce 8 partials + store; rotate active waves by chunk ----
        const int rw = (wave - chunk) & 7;
        if (rw < 2) {
            const int t2 = (rw << 6) + lane;
            const int r = t2 >> 4, d = t2 & 15;
            float o = 0.f;
            #pragma unroll
            for (int w = 0; w < 8; ++w) o += part[(w << 7) + t2];
            const float inv = 1.0f / sums[sb][r];
            const int q = qbase + r;
            const int h = head >> 3, bp = head & 7;
            float* dst = Ob + (((size_t)(h >> 1)) << 18)
                            + ((size_t)(((h & 1) << 9) + (q >> 1)) << 8)
                            + ((q & 1) << 7) + (bp << 4) + d;
            *dst = o * inv;
        }
    }
}

// ---------------------------------------------------------------------------
extern "C" void kernel_launch(void* const* d_in, const int* in_sizes, int n_in,
                              void* d_out, int out_size, void* d_ws, size_t ws_size,
                              hipStream_t stream) {
    const float* x  = (const float*)d_in[0];
    const float* y  = (const float*)d_in[1];
    const float* Wq = (const float*)d_in[2];
    const float* bq = (const float*)d_in[3];
    const float* Wk = (const float*)d_in[4];
    const float* bk = (const float*)d_in[5];
    const float* Wv = (const float*)d_in[6];
    const float* bv = (const float*)d_in[7];
    const float* Wo = (const float*)d_in[8];
    const float* bo = (const float*)d_in[9];
    float* out = (float*)d_out;

    float* Q  = (float*)d_ws;
    float* K  = Q + 2097152;
    float* V  = K + 2097152;
    float* AO = V + 2097152;

    gemmQKV<<<dim3(128, 4, 3), dim3(256), 0, stream>>>(x, y, Wq, bq, Wk, bk,
                                                       Wv, bv, Q, K, V);
    attn<<<dim3(128, 6), dim3(512), 0, stream>>>(Q, K, V, AO);
    gemmOut<<<dim3(128, 4), dim3(256), 0, stream>>>(AO, Wo, bo, out);
}